// Round 7
// baseline (1599.320 us; speedup 1.0000x reference)
//
#include <hip/hip_runtime.h>
#include <stdint.h>

#define B_ 4
#define T_ 4096
#define D_ 1024
#define H_ 8
#define K_ 128
#define V_ 128
#define F_ 4096
#define N_TOK (B_*T_)   // 16384

typedef unsigned short u16;
typedef __attribute__((ext_vector_type(8))) short bf16x8;
typedef __attribute__((ext_vector_type(4))) float f32x4;

__device__ __forceinline__ float bf2f(u16 u){
  unsigned x = ((unsigned)u) << 16;
  return __builtin_bit_cast(float, x);
}
__device__ __forceinline__ u16 f2bf(float f){
  unsigned x = __builtin_bit_cast(unsigned, f);
  x += 0x7FFFu + ((x >> 16) & 1u);   // RNE
  return (u16)(x >> 16);
}

// ---------------- transpose + downcast (f32 [R,C] -> bf16 [C,R]) ----------------
__global__ void transpose_k(const float* __restrict__ in, u16* __restrict__ out, int R, int C){
  __shared__ u16 tile[32][33];
  int c0 = blockIdx.x*32, r0 = blockIdx.y*32;
  int tx = threadIdx.x, ty = threadIdx.y;
  #pragma unroll
  for (int i = ty; i < 32; i += 8)
    tile[i][tx] = f2bf(in[(size_t)(r0+i)*C + c0 + tx]);
  __syncthreads();
  #pragma unroll
  for (int i = ty; i < 32; i += 8)
    out[(size_t)(c0+i)*R + r0 + tx] = tile[tx][i];
}

// ---------------- layernorm (row of 1024) ----------------
template<bool F32IN>
__global__ __launch_bounds__(256) void ln_k(const void* __restrict__ xv, const float* __restrict__ w,
                                            const float* __restrict__ bias, u16* __restrict__ out){
  __shared__ float ssh[4], qsh[4];
  int row = blockIdx.x; int t = threadIdx.x;
  float v0,v1,v2,v3;
  if constexpr (F32IN){
    const float* x = (const float*)xv;
    float4 r = ((const float4*)(x + (size_t)row*D_))[t];
    v0=r.x; v1=r.y; v2=r.z; v3=r.w;
  } else {
    const u16* x = (const u16*)xv;
    ushort4 r = ((const ushort4*)(x + (size_t)row*D_))[t];
    v0=bf2f(r.x); v1=bf2f(r.y); v2=bf2f(r.z); v3=bf2f(r.w);
  }
  float s = v0+v1+v2+v3;
  float q = v0*v0+v1*v1+v2*v2+v3*v3;
  #pragma unroll
  for (int m=1;m<64;m<<=1){ s += __shfl_xor(s,m); q += __shfl_xor(q,m); }
  int wave = t>>6, lane = t&63;
  if (lane==0){ ssh[wave]=s; qsh[wave]=q; }
  __syncthreads();
  s = ssh[0]+ssh[1]+ssh[2]+ssh[3];
  q = qsh[0]+qsh[1]+qsh[2]+qsh[3];
  float mean = s * (1.0f/D_);
  float var  = q * (1.0f/D_) - mean*mean;
  float inv  = rsqrtf(var + 1e-5f);
  float4 wr = ((const float4*)w)[t];
  float4 br = ((const float4*)bias)[t];
  ushort4 o;
  o.x = f2bf((v0-mean)*inv*wr.x + br.x);
  o.y = f2bf((v1-mean)*inv*wr.y + br.y);
  o.z = f2bf((v2-mean)*inv*wr.z + br.z);
  o.w = f2bf((v3-mean)*inv*wr.w + br.w);
  ((ushort4*)(out + (size_t)row*D_))[t] = o;
}

// ---------------- bf16 MFMA GEMM: C[M,N] = epi(A[M,K] @ Bt[N,K]^T) ----------------
template<int EPI, bool F32OUT>
__global__ __launch_bounds__(256,1)
void gemm_k(const u16* __restrict__ A, const u16* __restrict__ Bt, void* __restrict__ Cptr,
            int M, int N, int K,
            const float* __restrict__ fres, const u16* __restrict__ bres,
            const float* __restrict__ bias){
  __shared__ alignas(16) u16 As[128*32];
  __shared__ alignas(16) u16 Bs[128*32];
  int t = threadIdx.x;
  int wave = t>>6, lane = t&63;
  int lm = lane & 15, lq = lane >> 4;
  int m0 = blockIdx.y*128, n0 = blockIdx.x*128;
  int wm = (wave&1)*64, wn = (wave>>1)*64;

  const u16* Ag = A  + (size_t)(m0 + (t>>2))*K + (t&3)*8;
  const u16* Bg = Bt + (size_t)(n0 + (t>>2))*K + (t&3)*8;
  const size_t rstride = (size_t)64*K;

  f32x4 acc[4][4];
  #pragma unroll
  for (int i=0;i<4;i++)
    #pragma unroll
    for (int j=0;j<4;j++){ acc[i][j].x=0.f; acc[i][j].y=0.f; acc[i][j].z=0.f; acc[i][j].w=0.f; }

  uint4 ra0, ra1, rb0, rb1;
  auto loadRegs = [&](int kt){
    const u16* a = Ag + kt*32;
    const u16* b = Bg + kt*32;
    ra0 = *(const uint4*)a;             ra1 = *(const uint4*)(a + rstride);
    rb0 = *(const uint4*)b;             rb1 = *(const uint4*)(b + rstride);
  };
  loadRegs(0);

  u16* wA = As + t*8;
  u16* wB = Bs + t*8;
  const u16* rA = As + (size_t)(wm + lm)*32 + lq*8;
  const u16* rB = Bs + (size_t)(wn + lm)*32 + lq*8;

  int nk = K >> 5;
  for (int kt=0; kt<nk; ++kt){
    __syncthreads();
    *(uint4*)wA = ra0; *(uint4*)(wA+2048) = ra1;
    *(uint4*)wB = rb0; *(uint4*)(wB+2048) = rb1;
    __syncthreads();
    if (kt+1 < nk) loadRegs(kt+1);
    bf16x8 af[4], bfr[4];
    #pragma unroll
    for (int i=0;i<4;i++){
      af[i]  = *(const bf16x8*)(rA + i*16*32);
      bfr[i] = *(const bf16x8*)(rB + i*16*32);
    }
    #pragma unroll
    for (int i=0;i<4;i++)
      #pragma unroll
      for (int j=0;j<4;j++)
        acc[i][j] = __builtin_amdgcn_mfma_f32_16x16x32_bf16(af[i], bfr[j], acc[i][j], 0,0,0);
  }

  #pragma unroll
  for (int i=0;i<4;i++){
    int rbase = m0 + wm + i*16 + lq*4;
    #pragma unroll
    for (int j=0;j<4;j++){
      int col = n0 + wn + j*16 + lm;
      #pragma unroll
      for (int r=0;r<4;r++){
        float v = acc[i][j][r];
        size_t idx = (size_t)(rbase + r)*N + col;
        if (EPI==1) v += fres[idx];
        if (EPI==2){ v += bias[col]; v = 0.5f*v*(1.0f+erff(v*0.70710678118f)); }
        if (EPI==3){ v += bias[col] + bf2f(bres[idx]); }
        if constexpr (F32OUT) ((float*)Cptr)[idx] = v;
        else                  ((u16*)Cptr)[idx]  = f2bf(v);
      }
    }
  }
}

// ---------------- pack Wb|Wa -> wabT [16][1024] bf16 ----------------
__global__ __launch_bounds__(256) void wab_pack(const float* __restrict__ Wb, const float* __restrict__ Wa,
                                                u16* __restrict__ wabT){
  int g = blockIdx.x*256 + threadIdx.x;   // 16384 total
  int j = g >> 10, d = g & 1023;
  const float* W = (j < 8) ? Wb : Wa;
  wabT[g] = f2bf(W[(size_t)d*H_ + (j&7)]);
}

// ---------------- alpha/beta via MFMA: sigmoid(n @ [Wb|Wa]) ----------------
__global__ __launch_bounds__(256) void ab_k(const u16* __restrict__ n, const u16* __restrict__ wabT,
                                            float* __restrict__ beta, float* __restrict__ alpha){
  int tid = threadIdx.x, lane = tid&63, wv = tid>>6;
  int lm = lane & 15, lq = lane >> 4;
  int tok0 = (blockIdx.x*4 + wv)*16;
  const u16* np = n + (size_t)(tok0 + lm)*D_;
  const u16* wp = wabT + (size_t)lm*D_;
  f32x4 acc = {0.f,0.f,0.f,0.f};
  #pragma unroll
  for (int kt=0; kt<32; ++kt){
    bf16x8 af = *(const bf16x8*)(np + kt*32 + lq*8);
    bf16x8 bf = *(const bf16x8*)(wp + kt*32 + lq*8);
    acc = __builtin_amdgcn_mfma_f32_16x16x32_bf16(af, bf, acc, 0,0,0);
  }
  #pragma unroll
  for (int r=0;r<4;r++){
    int tok = tok0 + lq*4 + r;
    float sg = 1.f/(1.f+expf(-acc[r]));
    if (lm < 8) beta [(size_t)tok*H_ + lm]     = sg;
    else        alpha[(size_t)tok*H_ + lm - 8] = sg;
  }
}

// ---------------- activation: silu (+l2norm for q,k), in-place on q|k|v (bf16) ----------------
__global__ __launch_bounds__(128) void act_k(u16* __restrict__ qkv){
  __shared__ float tot[2];
  int y = blockIdx.y;
  int tok = blockIdx.x >> 3, head = blockIdx.x & 7;
  u16* p = qkv + (size_t)y*((size_t)N_TOK*D_) + (size_t)tok*D_ + head*K_ + threadIdx.x;
  float xv = bf2f(*p);
  float s = xv / (1.f + expf(-xv));
  if (y < 2){
    float sq = s*s;
    #pragma unroll
    for (int m=1;m<64;m<<=1) sq += __shfl_xor(sq,m);
    int wave = threadIdx.x >> 6;
    if ((threadIdx.x&63)==0) tot[wave]=sq;
    __syncthreads();
    s *= rsqrtf(tot[0]+tot[1] + 1e-6f);
  }
  *p = f2bf(s);
}

// ============ GDN chunked delta rule (C=64) ============
__global__ __launch_bounds__(256) void gdn_pre(const u16* __restrict__ k, const u16* __restrict__ q,
        const float* __restrict__ alpha, const float* __restrict__ beta,
        u16* __restrict__ T_all, u16* __restrict__ Att_all, float* __restrict__ cumg_all){
  __shared__ alignas(16) char sm[49664];
  u16*   Ks = (u16*)sm;                 // [64][128]
  u16*   Qs = (u16*)(sm+16384);         // [64][128]
  float* Tl = (float*)(sm+16384);       // [64][64] aliases Qs (used after Qs dead)
  float* Ml = (float*)(sm+32768);       // [64][64]
  float* cg = (float*)(sm+49152);       // [64]
  float* bv = (float*)(sm+49408);       // [64]
  int c = blockIdx.x, bh = blockIdx.y;
  int b = bh>>3, h = bh&7;
  int tid = threadIdx.x, lane = tid&63, wv = tid>>6;
  int q4 = lane>>4, n = lane&15;
  size_t rowbase = ((size_t)b*T_ + c*64);
  const u16* kg = k + rowbase*D_ + h*K_;
  const u16* qg = q + rowbase*D_ + h*K_;
  #pragma unroll
  for (int i=0;i<4;i++){
    int g = tid + i*256; int s = g>>4; int k8 = (g&15)*8;
    *(uint4*)&Ks[s*128+k8] = *(const uint4*)(kg + (size_t)s*D_ + k8);
    *(uint4*)&Qs[s*128+k8] = *(const uint4*)(qg + (size_t)s*D_ + k8);
  }
  if (tid < 64){
    float a = alpha[(rowbase+tid)*H_ + h];
    bv[tid] = beta[(rowbase+tid)*H_ + h];
    float xx = a;
    #pragma unroll
    for (int d=1; d<64; d<<=1){
      float y = __shfl_up(xx, (unsigned)d);
      if (tid >= d) xx *= y;
    }
    cg[tid] = xx;
    cumg_all[((size_t)c*32+bh)*64 + tid] = xx;
  }
  __syncthreads();
  f32x4 kk[4], qk[4];
  #pragma unroll
  for (int nb=0; nb<4; nb++){
    f32x4 a1={0,0,0,0}, a2={0,0,0,0};
    #pragma unroll
    for (int ks=0; ks<4; ks++){
      bf16x8 af = *(const bf16x8*)&Ks[(16*wv+n)*128 + ks*32 + q4*8];
      bf16x8 qf = *(const bf16x8*)&Qs[(16*wv+n)*128 + ks*32 + q4*8];
      bf16x8 bf = *(const bf16x8*)&Ks[(16*nb+n)*128 + ks*32 + q4*8];
      a1 = __builtin_amdgcn_mfma_f32_16x16x32_bf16(af, bf, a1, 0,0,0);
      a2 = __builtin_amdgcn_mfma_f32_16x16x32_bf16(qf, bf, a2, 0,0,0);
    }
    kk[nb]=a1; qk[nb]=a2;
  }
  __syncthreads();   // Qs reads done -> Tl may reuse region
  size_t gbase = ((size_t)c*32+bh)*4096;
  #pragma unroll
  for (int nb=0; nb<4; nb++){
    #pragma unroll
    for (int r=0;r<4;r++){
      int srow = 16*wv + 4*q4 + r;
      int scol = 16*nb + n;
      float m = 0.f, at = 0.f;
      if (scol <= srow){
        float rb = (cg[srow]/cg[scol]) * bv[scol];
        at = rb * qk[nb][r];
        if (scol < srow) m = rb * kk[nb][r];
      }
      Ml[srow*64 + scol] = m;
      Att_all[gbase + srow*64 + scol] = f2bf(at);
    }
  }
  #pragma unroll
  for (int i=0;i<16;i++){
    int g = tid + i*256;
    Tl[g] = ((g>>6) == (g&63)) ? 1.f : 0.f;
  }
  __syncthreads();
  if (tid < 64){
    int j = tid;
    for (int s=1; s<64; ++s){
      float acc = 0.f;
      for (int r=0; r<s; ++r)
        acc += Ml[s*64+r] * Tl[r*64+j];
      Tl[s*64+j] -= acc;
    }
  }
  __syncthreads();
  #pragma unroll
  for (int i=0;i<16;i++){
    int g = tid + i*256;
    T_all[gbase + g] = f2bf(Tl[g]);
  }
}

// gdn_scan: sequential over 64 chunks per (bh, v-half). S[128 x 64cols] in f32 regs.
// Register-prefetch double-buffer of next chunk's staging; Kt rotate-swizzled:
// addr(k,t) = k*72 + ((t + 8*(k>>3)) & 63)  (b128 reads stay aligned; writes ~2-way banked)
__global__ __launch_bounds__(256,1) void gdn_scan(const u16* __restrict__ q, const u16* __restrict__ k,
        const u16* __restrict__ v, const float* __restrict__ beta,
        const u16* __restrict__ T_all, const u16* __restrict__ Att_all,
        const float* __restrict__ cumg_all, u16* __restrict__ o){
  __shared__ alignas(16) char sm[64000];
  u16* Kt  = (u16*)sm;              // [128][72] K^T (swizzled)
  u16* Ts  = (u16*)(sm+18432);      // [64][72]
  u16* As_ = (u16*)(sm+27648);      // [64][72]
  u16* Sbt = (u16*)(sm+36864);      // [64 cols][136 rows] S bf16, transposed
  u16* RUt = (u16*)(sm+54272);      // [64 cols][72 rows]  R -> U -> U'' transposed
  float* cg = (float*)(sm+63488);
  float* bv = (float*)(sm+63744);
  int bh = blockIdx.x, half = blockIdx.y;
  int b = bh>>3, h = bh&7;
  int tid = threadIdx.x, lane = tid&63, wv = tid>>6;
  int q4 = lane>>4, n = lane&15;
  int colb = half*64 + wv*16;       // this wave's v-col base
  f32x4 Sa[8];
  #pragma unroll
  for (int i=0;i<8;i++) Sa[i] = (f32x4){0.f,0.f,0.f,0.f};

  // prefetch registers (chunk c+1 staging)
  uint4 kv[4], tv[2], av[2];
  u16 vvv[16];
  float cgr = 0.f, bvr = 0.f;

  auto prefetch = [&](int c){
    size_t rowbase = ((size_t)b*T_ + c*64);
    const u16* kg = k + rowbase*D_ + h*K_;
    #pragma unroll
    for (int i=0;i<4;i++){
      int g = tid + i*256; int s = g>>4; int k8 = (g&15)*8;
      kv[i] = *(const uint4*)(kg + (size_t)s*D_ + k8);
    }
    size_t tb = ((size_t)c*32+bh)*4096;
    #pragma unroll
    for (int i=0;i<2;i++){
      int g = tid+i*256; int r = g>>3; int c8=(g&7)*8;
      tv[i] = *(const uint4*)(T_all  + tb + r*64 + c8);
      av[i] = *(const uint4*)(Att_all + tb + r*64 + c8);
    }
    const u16* vg = v + rowbase*D_ + h*V_ + colb + n;
    #pragma unroll
    for (int mb=0; mb<4; mb++)
      #pragma unroll
      for (int r=0;r<4;r++)
        vvv[mb*4+r] = vg[(size_t)(16*mb+4*q4+r)*D_];
    if (tid < 64){
      cgr = cumg_all[((size_t)c*32+bh)*64 + tid];
      bvr = beta[(rowbase+tid)*H_ + h];
    }
  };

  prefetch(0);

  for (int c=0; c<64; ++c){
    size_t rowbase = ((size_t)b*T_ + c*64);
    const u16* kg = k + rowbase*D_ + h*K_;
    const u16* qg = q + rowbase*D_ + h*K_;

    // ---- write staged regs -> LDS ----
    // Kt: pair lanes (s even, s odd) via shfl_xor(16) -> b32 writes of (t0,t0+1)
    #pragma unroll
    for (int i=0;i<4;i++){
      int g = tid + i*256; int s = g>>4; int kb8 = (g&15)*8;
      uint4 pv;
      pv.x = (unsigned)__shfl_xor((int)kv[i].x, 16);
      pv.y = (unsigned)__shfl_xor((int)kv[i].y, 16);
      pv.z = (unsigned)__shfl_xor((int)kv[i].z, 16);
      pv.w = (unsigned)__shfl_xor((int)kv[i].w, 16);
      int odd = s & 1;                 // s_base even, so odd = (lane>>4)&1
      int t0  = s & ~1;
      int jb  = odd ? 4 : 0;
      int rot = (8*(g&15)) & 63;       // 8*(k>>3), same for j<8
      const u16* own = (const u16*)&kv[i];
      const u16* par = (const u16*)&pv;
      #pragma unroll
      for (int j=0;j<4;j++){
        int jj = jb + j;
        unsigned lo = odd ? par[jj] : own[jj];
        unsigned hi = odd ? own[jj] : par[jj];
        int addr = (kb8+jj)*72 + ((t0 + rot) & 63);   // even -> b32-aligned
        *(unsigned*)&Kt[addr] = lo | (hi << 16);
      }
    }
    #pragma unroll
    for (int i=0;i<2;i++){
      int g = tid+i*256; int r = g>>3; int c8=(g&7)*8;
      *(uint4*)&Ts[r*72+c8]  = tv[i];
      *(uint4*)&As_[r*72+c8] = av[i];
    }
    if (tid < 64){ cg[tid] = cgr; bv[tid] = bvr; }

    float vreg[16];
    #pragma unroll
    for (int i=0;i<16;i++) vreg[i] = bf2f(vvv[i]);

    // S0 -> bf16 transposed LDS (wave-local region)
    #pragma unroll
    for (int mb=0; mb<8; mb++){
      ushort4 w4;
      w4.x=f2bf(Sa[mb][0]); w4.y=f2bf(Sa[mb][1]); w4.z=f2bf(Sa[mb][2]); w4.w=f2bf(Sa[mb][3]);
      *(ushort4*)&Sbt[(wv*16+n)*136 + mb*16 + q4*4] = w4;
    }
    __syncthreads();

    if (c+1 < 64) prefetch(c+1);   // in flight across the whole compute phase

    // ---- P = K*S0, Oq = Q*S0 (A-frags from global; K is L1/L2-warm from prefetch) ----
    f32x4 Pa[4], Oqa[4];
    #pragma unroll
    for (int mb=0; mb<4; mb++){
      f32x4 p={0,0,0,0}, oq={0,0,0,0};
      #pragma unroll
      for (int ks=0; ks<4; ks++){
        bf16x8 ak = *(const bf16x8*)(kg + (size_t)(16*mb+n)*D_ + ks*32 + q4*8);
        bf16x8 aq = *(const bf16x8*)(qg + (size_t)(16*mb+n)*D_ + ks*32 + q4*8);
        bf16x8 bs = *(const bf16x8*)&Sbt[(wv*16+n)*136 + ks*32 + q4*8];
        p  = __builtin_amdgcn_mfma_f32_16x16x32_bf16(ak, bs, p, 0,0,0);
        oq = __builtin_amdgcn_mfma_f32_16x16x32_bf16(aq, bs, oq, 0,0,0);
      }
      Pa[mb]=p; Oqa[mb]=oq;
    }
    // ---- R = V - diag(g)P -> RUt ----
    #pragma unroll
    for (int mb=0; mb<4; mb++){
      ushort4 w4;
      #pragma unroll
      for (int r=0;r<4;r++){
        int t = 16*mb+4*q4+r;
        ((u16*)&w4)[r] = f2bf(vreg[mb*4+r] - cg[t]*Pa[mb][r]);
      }
      *(ushort4*)&RUt[(wv*16+n)*72 + mb*16 + q4*4] = w4;
    }
    // ---- U = T*R ----
    f32x4 Ua[4];
    #pragma unroll
    for (int mb=0; mb<4; mb++){
      f32x4 u={0,0,0,0};
      #pragma unroll
      for (int ks=0; ks<2; ks++){
        bf16x8 at = *(const bf16x8*)&Ts[(16*mb+n)*72 + ks*32 + q4*8];
        bf16x8 br = *(const bf16x8*)&RUt[(wv*16+n)*72 + ks*32 + q4*8];
        u = __builtin_amdgcn_mfma_f32_16x16x32_bf16(at, br, u, 0,0,0);
      }
      Ua[mb]=u;
    }
    // ---- raw U over RUt (for Att*U) ----
    #pragma unroll
    for (int mb=0; mb<4; mb++){
      ushort4 w4;
      #pragma unroll
      for (int r=0;r<4;r++) ((u16*)&w4)[r] = f2bf(Ua[mb][r]);
      *(ushort4*)&RUt[(wv*16+n)*72 + mb*16 + q4*4] = w4;
    }
    // ---- O = diag(g)Oq + Att*U ; store ----
    u16* og = o + rowbase*D_ + h*V_ + colb + n;
    #pragma unroll
    for (int mb=0; mb<4; mb++){
      f32x4 oa={0,0,0,0};
      #pragma unroll
      for (int ks=0; ks<2; ks++){
        bf16x8 aa = *(const bf16x8*)&As_[(16*mb+n)*72 + ks*32 + q4*8];
        bf16x8 bu = *(const bf16x8*)&RUt[(wv*16+n)*72 + ks*32 + q4*8];
        oa = __builtin_amdgcn_mfma_f32_16x16x32_bf16(aa, bu, oa, 0,0,0);
      }
      #pragma unroll
      for (int r=0;r<4;r++){
        int t = 16*mb+4*q4+r;
        og[(size_t)t*D_] = f2bf(cg[t]*Oqa[mb][r] + oa[r]);
      }
    }
    // ---- U'' = diag(gC*b/g) U over RUt ----
    float gC = cg[63];
    #pragma unroll
    for (int mb=0; mb<4; mb++){
      ushort4 w4;
      #pragma unroll
      for (int r=0;r<4;r++){
        int t = 16*mb+4*q4+r;
        ((u16*)&w4)[r] = f2bf((gC/cg[t])*bv[t]*Ua[mb][r]);
      }
      *(ushort4*)&RUt[(wv*16+n)*72 + mb*16 + q4*4] = w4;
    }
    // ---- S = gC*S + K^T * U'' (Kt reads use the rotate swizzle) ----
    #pragma unroll
    for (int mb=0; mb<8; mb++){
      f32x4 s = Sa[mb]*gC;
      int krow = 16*mb + n;
      int rot  = (16*mb + 8*(n>>3)) & 63;     // 8*(krow>>3) & 63
      #pragma unroll
      for (int ks=0; ks<2; ks++){
        int tt = (ks*32 + q4*8 + rot) & 63;
        bf16x8 akt = *(const bf16x8*)&Kt[krow*72 + tt];
        bf16x8 bu  = *(const bf16x8*)&RUt[(wv*16+n)*72 + ks*32 + q4*8];
        s = __builtin_amdgcn_mfma_f32_16x16x32_bf16(akt, bu, s, 0,0,0);
      }
      Sa[mb]=s;
    }
    __syncthreads();
  }
}

// ---------------- launch ----------------
extern "C" void kernel_launch(void* const* d_in, const int* in_sizes, int n_in,
                              void* d_out, int out_size, void* d_ws, size_t ws_size,
                              hipStream_t stream){
  const float* x    = (const float*)d_in[0];
  const float* Wq   = (const float*)d_in[1];
  const float* Wk   = (const float*)d_in[2];
  const float* Wv   = (const float*)d_in[3];
  const float* Wb   = (const float*)d_in[4];
  const float* Wa   = (const float*)d_in[5];
  const float* Wo   = (const float*)d_in[6];
  const float* ln1w = (const float*)d_in[7];
  const float* ln1b = (const float*)d_in[8];
  const float* ln2w = (const float*)d_in[9];
  const float* ln2b = (const float*)d_in[10];
  const float* W1   = (const float*)d_in[11];
  const float* b1   = (const float*)d_in[12];
  const float* W2   = (const float*)d_in[13];
  const float* b2   = (const float*)d_in[14];

  char* ws = (char*)d_ws;
  size_t off = 0;
  auto alloc = [&](size_t bytes)->char*{
    char* p = ws + off; off += (bytes + 255) & ~(size_t)255; return p;
  };
  u16* WqT = (u16*)alloc((size_t)1024*1024*2);
  u16* WkT = (u16*)alloc((size_t)1024*1024*2);
  u16* WvT = (u16*)alloc((size_t)1024*1024*2);
  u16* WoT = (u16*)alloc((size_t)1024*1024*2);
  u16* W1T = (u16*)alloc((size_t)4096*1024*2);
  u16* W2T = (u16*)alloc((size_t)1024*4096*2);
  u16* wabT = (u16*)alloc((size_t)16*1024*2);
  float* alphaB = (float*)alloc((size_t)N_TOK*H_*4);
  float* betaB  = (float*)alloc((size_t)N_TOK*H_*4);
  u16* x1 = (u16*)alloc((size_t)N_TOK*D_*2);
  u16* n1 = (u16*)alloc((size_t)N_TOK*D_*2);          // also reused: T_all+Att_all, then h (ln2 out)
  u16* qb = (u16*)alloc((size_t)N_TOK*D_*2);          // q,k,v,o contiguous (act_k relies on it)
  u16* kb = (u16*)alloc((size_t)N_TOK*D_*2);
  u16* vb = (u16*)alloc((size_t)N_TOK*D_*2);
  u16* ob = (u16*)alloc((size_t)N_TOK*D_*2);
  u16* ffa = qb;                                      // [N_TOK,4096] aliases q/k/v/o (dead by then)
  if (ws_size < off) return;

  u16*   T_all   = n1;                                 // 2048*4096 bf16 = 16.78 MB
  u16*   Att_all = n1 + (size_t)2048*4096;             // 16.78 MB
  float* cumg    = (float*)x1;                         // 0.5 MB (x1 dead till Wo-gemm)

  dim3 tb(32,8);
  transpose_k<<<dim3(32,32),  tb, 0, stream>>>(Wq, WqT, 1024, 1024);
  transpose_k<<<dim3(32,32),  tb, 0, stream>>>(Wk, WkT, 1024, 1024);
  transpose_k<<<dim3(32,32),  tb, 0, stream>>>(Wv, WvT, 1024, 1024);
  transpose_k<<<dim3(32,32),  tb, 0, stream>>>(Wo, WoT, 1024, 1024);
  transpose_k<<<dim3(128,32), tb, 0, stream>>>(W1, W1T, 1024, 4096);
  transpose_k<<<dim3(32,128), tb, 0, stream>>>(W2, W2T, 4096, 1024);
  wab_pack<<<64, 256, 0, stream>>>(Wb, Wa, wabT);

  ln_k<true><<<N_TOK, 256, 0, stream>>>(x, ln1w, ln1b, n1);

  gemm_k<0,false><<<dim3(8,128), 256, 0, stream>>>(n1, WqT, qb, N_TOK, 1024, 1024, nullptr, nullptr, nullptr);
  gemm_k<0,false><<<dim3(8,128), 256, 0, stream>>>(n1, WkT, kb, N_TOK, 1024, 1024, nullptr, nullptr, nullptr);
  gemm_k<0,false><<<dim3(8,128), 256, 0, stream>>>(n1, WvT, vb, N_TOK, 1024, 1024, nullptr, nullptr, nullptr);
  ab_k<<<256, 256, 0, stream>>>(n1, wabT, betaB, alphaB);
  act_k<<<dim3(N_TOK*H_, 3), 128, 0, stream>>>(qb);

  gdn_pre <<<dim3(64,32), 256, 0, stream>>>(kb, qb, alphaB, betaB, T_all, Att_all, cumg);
  gdn_scan<<<dim3(32,2),  256, 0, stream>>>(qb, kb, vb, betaB, T_all, Att_all, cumg, ob);

  gemm_k<1,false><<<dim3(8,128), 256, 0, stream>>>(ob, WoT, x1, N_TOK, 1024, 1024, x, nullptr, nullptr);
  ln_k<false><<<N_TOK, 256, 0, stream>>>(x1, ln2w, ln2b, n1);
  gemm_k<2,false><<<dim3(32,128), 256, 0, stream>>>(n1, W1T, ffa, N_TOK, 4096, 1024, nullptr, nullptr, b1);
  gemm_k<3,true><<<dim3(8,128), 256, 0, stream>>>(ffa, W2T, d_out, N_TOK, 1024, 4096, nullptr, x1, b2);
}

// Round 8
// 1441.635 us; speedup vs baseline: 1.1094x; 1.1094x over previous
//
#include <hip/hip_runtime.h>
#include <stdint.h>

#define B_ 4
#define T_ 4096
#define D_ 1024
#define H_ 8
#define K_ 128
#define V_ 128
#define F_ 4096
#define N_TOK (B_*T_)   // 16384

typedef unsigned short u16;
typedef __attribute__((ext_vector_type(8))) short bf16x8;
typedef __attribute__((ext_vector_type(4))) float f32x4;

__device__ __forceinline__ float bf2f(u16 u){
  unsigned x = ((unsigned)u) << 16;
  return __builtin_bit_cast(float, x);
}
__device__ __forceinline__ u16 f2bf(float f){
  unsigned x = __builtin_bit_cast(unsigned, f);
  x += 0x7FFFu + ((x >> 16) & 1u);   // RNE
  return (u16)(x >> 16);
}

// ---------------- transpose + downcast (f32 [R,C] -> bf16 [C,R]) ----------------
__global__ void transpose_k(const float* __restrict__ in, u16* __restrict__ out, int R, int C){
  __shared__ u16 tile[32][33];
  int c0 = blockIdx.x*32, r0 = blockIdx.y*32;
  int tx = threadIdx.x, ty = threadIdx.y;
  #pragma unroll
  for (int i = ty; i < 32; i += 8)
    tile[i][tx] = f2bf(in[(size_t)(r0+i)*C + c0 + tx]);
  __syncthreads();
  #pragma unroll
  for (int i = ty; i < 32; i += 8)
    out[(size_t)(c0+i)*R + r0 + tx] = tile[tx][i];
}

// ---------------- layernorm (row of 1024) ----------------
template<bool F32IN>
__global__ __launch_bounds__(256) void ln_k(const void* __restrict__ xv, const float* __restrict__ w,
                                            const float* __restrict__ bias, u16* __restrict__ out){
  __shared__ float ssh[4], qsh[4];
  int row = blockIdx.x; int t = threadIdx.x;
  float v0,v1,v2,v3;
  if constexpr (F32IN){
    const float* x = (const float*)xv;
    float4 r = ((const float4*)(x + (size_t)row*D_))[t];
    v0=r.x; v1=r.y; v2=r.z; v3=r.w;
  } else {
    const u16* x = (const u16*)xv;
    ushort4 r = ((const ushort4*)(x + (size_t)row*D_))[t];
    v0=bf2f(r.x); v1=bf2f(r.y); v2=bf2f(r.z); v3=bf2f(r.w);
  }
  float s = v0+v1+v2+v3;
  float q = v0*v0+v1*v1+v2*v2+v3*v3;
  #pragma unroll
  for (int m=1;m<64;m<<=1){ s += __shfl_xor(s,m); q += __shfl_xor(q,m); }
  int wave = t>>6, lane = t&63;
  if (lane==0){ ssh[wave]=s; qsh[wave]=q; }
  __syncthreads();
  s = ssh[0]+ssh[1]+ssh[2]+ssh[3];
  q = qsh[0]+qsh[1]+qsh[2]+qsh[3];
  float mean = s * (1.0f/D_);
  float var  = q * (1.0f/D_) - mean*mean;
  float inv  = rsqrtf(var + 1e-5f);
  float4 wr = ((const float4*)w)[t];
  float4 br = ((const float4*)bias)[t];
  ushort4 o;
  o.x = f2bf((v0-mean)*inv*wr.x + br.x);
  o.y = f2bf((v1-mean)*inv*wr.y + br.y);
  o.z = f2bf((v2-mean)*inv*wr.z + br.z);
  o.w = f2bf((v3-mean)*inv*wr.w + br.w);
  ((ushort4*)(out + (size_t)row*D_))[t] = o;
}

// ---------------- bf16 MFMA GEMM: C[M,N] = epi(A[M,K] @ Bt[N,K]^T) ----------------
template<int EPI, bool F32OUT>
__global__ __launch_bounds__(256,1)
void gemm_k(const u16* __restrict__ A, const u16* __restrict__ Bt, void* __restrict__ Cptr,
            int M, int N, int K,
            const float* __restrict__ fres, const u16* __restrict__ bres,
            const float* __restrict__ bias){
  __shared__ alignas(16) u16 As[128*32];
  __shared__ alignas(16) u16 Bs[128*32];
  int t = threadIdx.x;
  int wave = t>>6, lane = t&63;
  int lm = lane & 15, lq = lane >> 4;
  int m0 = blockIdx.y*128, n0 = blockIdx.x*128;
  int wm = (wave&1)*64, wn = (wave>>1)*64;

  const u16* Ag = A  + (size_t)(m0 + (t>>2))*K + (t&3)*8;
  const u16* Bg = Bt + (size_t)(n0 + (t>>2))*K + (t&3)*8;
  const size_t rstride = (size_t)64*K;

  f32x4 acc[4][4];
  #pragma unroll
  for (int i=0;i<4;i++)
    #pragma unroll
    for (int j=0;j<4;j++){ acc[i][j].x=0.f; acc[i][j].y=0.f; acc[i][j].z=0.f; acc[i][j].w=0.f; }

  uint4 ra0, ra1, rb0, rb1;
  auto loadRegs = [&](int kt){
    const u16* a = Ag + kt*32;
    const u16* b = Bg + kt*32;
    ra0 = *(const uint4*)a;             ra1 = *(const uint4*)(a + rstride);
    rb0 = *(const uint4*)b;             rb1 = *(const uint4*)(b + rstride);
  };
  loadRegs(0);

  u16* wA = As + t*8;
  u16* wB = Bs + t*8;
  const u16* rA = As + (size_t)(wm + lm)*32 + lq*8;
  const u16* rB = Bs + (size_t)(wn + lm)*32 + lq*8;

  int nk = K >> 5;
  for (int kt=0; kt<nk; ++kt){
    __syncthreads();
    *(uint4*)wA = ra0; *(uint4*)(wA+2048) = ra1;
    *(uint4*)wB = rb0; *(uint4*)(wB+2048) = rb1;
    __syncthreads();
    if (kt+1 < nk) loadRegs(kt+1);
    bf16x8 af[4], bfr[4];
    #pragma unroll
    for (int i=0;i<4;i++){
      af[i]  = *(const bf16x8*)(rA + i*16*32);
      bfr[i] = *(const bf16x8*)(rB + i*16*32);
    }
    #pragma unroll
    for (int i=0;i<4;i++)
      #pragma unroll
      for (int j=0;j<4;j++)
        acc[i][j] = __builtin_amdgcn_mfma_f32_16x16x32_bf16(af[i], bfr[j], acc[i][j], 0,0,0);
  }

  #pragma unroll
  for (int i=0;i<4;i++){
    int rbase = m0 + wm + i*16 + lq*4;
    #pragma unroll
    for (int j=0;j<4;j++){
      int col = n0 + wn + j*16 + lm;
      #pragma unroll
      for (int r=0;r<4;r++){
        float v = acc[i][j][r];
        size_t idx = (size_t)(rbase + r)*N + col;
        if (EPI==1) v += fres[idx];
        if (EPI==2){ v += bias[col]; v = 0.5f*v*(1.0f+erff(v*0.70710678118f)); }
        if (EPI==3){ v += bias[col] + bf2f(bres[idx]); }
        if constexpr (F32OUT) ((float*)Cptr)[idx] = v;
        else                  ((u16*)Cptr)[idx]  = f2bf(v);
      }
    }
  }
}

// ---------------- pack Wb|Wa -> wabT [16][1024] bf16 ----------------
__global__ __launch_bounds__(256) void wab_pack(const float* __restrict__ Wb, const float* __restrict__ Wa,
                                                u16* __restrict__ wabT){
  int g = blockIdx.x*256 + threadIdx.x;   // 16384 total
  int j = g >> 10, d = g & 1023;
  const float* W = (j < 8) ? Wb : Wa;
  wabT[g] = f2bf(W[(size_t)d*H_ + (j&7)]);
}

// ---------------- alpha/beta via MFMA: sigmoid(n @ [Wb|Wa]) ----------------
__global__ __launch_bounds__(256) void ab_k(const u16* __restrict__ n, const u16* __restrict__ wabT,
                                            float* __restrict__ beta, float* __restrict__ alpha){
  int tid = threadIdx.x, lane = tid&63, wv = tid>>6;
  int lm = lane & 15, lq = lane >> 4;
  int tok0 = (blockIdx.x*4 + wv)*16;
  const u16* np = n + (size_t)(tok0 + lm)*D_;
  const u16* wp = wabT + (size_t)lm*D_;
  f32x4 acc = {0.f,0.f,0.f,0.f};
  #pragma unroll
  for (int kt=0; kt<32; ++kt){
    bf16x8 af = *(const bf16x8*)(np + kt*32 + lq*8);
    bf16x8 bf = *(const bf16x8*)(wp + kt*32 + lq*8);
    acc = __builtin_amdgcn_mfma_f32_16x16x32_bf16(af, bf, acc, 0,0,0);
  }
  #pragma unroll
  for (int r=0;r<4;r++){
    int tok = tok0 + lq*4 + r;
    float sg = 1.f/(1.f+expf(-acc[r]));
    if (lm < 8) beta [(size_t)tok*H_ + lm]     = sg;
    else        alpha[(size_t)tok*H_ + lm - 8] = sg;
  }
}

// ---------------- activation: silu (+l2norm for q,k), in-place on q|k|v (bf16) ----------------
__global__ __launch_bounds__(128) void act_k(u16* __restrict__ qkv){
  __shared__ float tot[2];
  int y = blockIdx.y;
  int tok = blockIdx.x >> 3, head = blockIdx.x & 7;
  u16* p = qkv + (size_t)y*((size_t)N_TOK*D_) + (size_t)tok*D_ + head*K_ + threadIdx.x;
  float xv = bf2f(*p);
  float s = xv / (1.f + expf(-xv));
  if (y < 2){
    float sq = s*s;
    #pragma unroll
    for (int m=1;m<64;m<<=1) sq += __shfl_xor(sq,m);
    int wave = threadIdx.x >> 6;
    if ((threadIdx.x&63)==0) tot[wave]=sq;
    __syncthreads();
    s *= rsqrtf(tot[0]+tot[1] + 1e-6f);
  }
  *p = f2bf(s);
}

// ============ GDN chunked delta rule (C=64) ============
__global__ __launch_bounds__(256) void gdn_pre(const u16* __restrict__ k, const u16* __restrict__ q,
        const float* __restrict__ alpha, const float* __restrict__ beta,
        u16* __restrict__ T_all, u16* __restrict__ Att_all, float* __restrict__ cumg_all){
  __shared__ alignas(16) char sm[49664];
  u16*   Ks = (u16*)sm;                 // [64][128]
  u16*   Qs = (u16*)(sm+16384);         // [64][128]
  float* Tl = (float*)(sm+16384);       // [64][64] aliases Qs (used after Qs dead)
  float* Ml = (float*)(sm+32768);       // [64][64]
  float* cg = (float*)(sm+49152);       // [64]
  float* bv = (float*)(sm+49408);       // [64]
  int c = blockIdx.x, bh = blockIdx.y;
  int b = bh>>3, h = bh&7;
  int tid = threadIdx.x, lane = tid&63, wv = tid>>6;
  int q4 = lane>>4, n = lane&15;
  size_t rowbase = ((size_t)b*T_ + c*64);
  const u16* kg = k + rowbase*D_ + h*K_;
  const u16* qg = q + rowbase*D_ + h*K_;
  #pragma unroll
  for (int i=0;i<4;i++){
    int g = tid + i*256; int s = g>>4; int k8 = (g&15)*8;
    *(uint4*)&Ks[s*128+k8] = *(const uint4*)(kg + (size_t)s*D_ + k8);
    *(uint4*)&Qs[s*128+k8] = *(const uint4*)(qg + (size_t)s*D_ + k8);
  }
  if (tid < 64){
    float a = alpha[(rowbase+tid)*H_ + h];
    bv[tid] = beta[(rowbase+tid)*H_ + h];
    float xx = a;
    #pragma unroll
    for (int d=1; d<64; d<<=1){
      float y = __shfl_up(xx, (unsigned)d);
      if (tid >= d) xx *= y;
    }
    cg[tid] = xx;
    cumg_all[((size_t)c*32+bh)*64 + tid] = xx;
  }
  __syncthreads();
  f32x4 kk[4], qk[4];
  #pragma unroll
  for (int nb=0; nb<4; nb++){
    f32x4 a1={0,0,0,0}, a2={0,0,0,0};
    #pragma unroll
    for (int ks=0; ks<4; ks++){
      bf16x8 af = *(const bf16x8*)&Ks[(16*wv+n)*128 + ks*32 + q4*8];
      bf16x8 qf = *(const bf16x8*)&Qs[(16*wv+n)*128 + ks*32 + q4*8];
      bf16x8 bf = *(const bf16x8*)&Ks[(16*nb+n)*128 + ks*32 + q4*8];
      a1 = __builtin_amdgcn_mfma_f32_16x16x32_bf16(af, bf, a1, 0,0,0);
      a2 = __builtin_amdgcn_mfma_f32_16x16x32_bf16(qf, bf, a2, 0,0,0);
    }
    kk[nb]=a1; qk[nb]=a2;
  }
  __syncthreads();   // Qs reads done -> Tl may reuse region
  size_t gbase = ((size_t)c*32+bh)*4096;
  #pragma unroll
  for (int nb=0; nb<4; nb++){
    #pragma unroll
    for (int r=0;r<4;r++){
      int srow = 16*wv + 4*q4 + r;
      int scol = 16*nb + n;
      float m = 0.f, at = 0.f;
      if (scol <= srow){
        float rb = (cg[srow]/cg[scol]) * bv[scol];
        at = rb * qk[nb][r];
        if (scol < srow) m = rb * kk[nb][r];
      }
      Ml[srow*64 + scol] = m;
      Att_all[gbase + srow*64 + scol] = f2bf(at);
    }
  }
  #pragma unroll
  for (int i=0;i<16;i++){
    int g = tid + i*256;
    Tl[g] = ((g>>6) == (g&63)) ? 1.f : 0.f;
  }
  __syncthreads();
  if (tid < 64){
    int j = tid;
    for (int s=1; s<64; ++s){
      float acc = 0.f;
      for (int r=0; r<s; ++r)
        acc += Ml[s*64+r] * Tl[r*64+j];
      Tl[s*64+j] -= acc;
    }
  }
  __syncthreads();
  #pragma unroll
  for (int i=0;i<16;i++){
    int g = tid + i*256;
    T_all[gbase + g] = f2bf(Tl[g]);
  }
}

// gdn_scan: sequential over 64 chunks per (bh, v-half). S[128 x 64cols] in f32 regs.
// ALL compute-phase operands are LDS-resident; the only global ops in steady state are
// the register prefetch of chunk c+1 (one overlapped vmcnt wait) and the O store.
__global__ __launch_bounds__(256,1) void gdn_scan(const u16* __restrict__ q, const u16* __restrict__ k,
        const u16* __restrict__ v, const float* __restrict__ beta,
        const u16* __restrict__ T_all, const u16* __restrict__ Att_all,
        const float* __restrict__ cumg_all, u16* __restrict__ o){
  __shared__ alignas(16) char sm[89600];
  u16* Ksh = (u16*)sm;               // [64][136] K row-major
  u16* Qsh = (u16*)(sm+17408);       // [64][136] Q row-major
  u16* Kt  = (u16*)(sm+34816);       // [128][72] K^T (rotate-swizzled)
  u16* Ts  = (u16*)(sm+53248);       // [64][72]
  u16* As_ = (u16*)(sm+62464);       // [64][72]
  u16* Sbt = (u16*)(sm+71680);       // [64 cols][136] S0^T bf16; RUt aliases offsets 0..71
  u16* RUt = (u16*)(sm+71680);       // alias (S0 consumed by stage 1 before first RUt write)
  float* cg = (float*)(sm+89088);
  float* bv = (float*)(sm+89344);
  int bh = blockIdx.x, half = blockIdx.y;
  int b = bh>>3, h = bh&7;
  int tid = threadIdx.x, lane = tid&63, wv = tid>>6;
  int q4 = lane>>4, n = lane&15;
  int colb = half*64 + wv*16;       // this wave's v-col base
  f32x4 Sa[8];
  #pragma unroll
  for (int i=0;i<8;i++) Sa[i] = (f32x4){0.f,0.f,0.f,0.f};

  // prefetch registers (chunk c+1 staging)
  uint4 kv[4], qv[4], tv[2], av[2];
  u16 vvv[16];
  float cgr = 0.f, bvr = 0.f;

  auto prefetch = [&](int c){
    size_t rowbase = ((size_t)b*T_ + c*64);
    const u16* kg = k + rowbase*D_ + h*K_;
    const u16* qg = q + rowbase*D_ + h*K_;
    #pragma unroll
    for (int i=0;i<4;i++){
      int g = tid + i*256; int s = g>>4; int k8 = (g&15)*8;
      kv[i] = *(const uint4*)(kg + (size_t)s*D_ + k8);
      qv[i] = *(const uint4*)(qg + (size_t)s*D_ + k8);
    }
    size_t tb = ((size_t)c*32+bh)*4096;
    #pragma unroll
    for (int i=0;i<2;i++){
      int g = tid+i*256; int r = g>>3; int c8=(g&7)*8;
      tv[i] = *(const uint4*)(T_all  + tb + r*64 + c8);
      av[i] = *(const uint4*)(Att_all + tb + r*64 + c8);
    }
    const u16* vg = v + rowbase*D_ + h*V_ + colb + n;
    #pragma unroll
    for (int mb=0; mb<4; mb++)
      #pragma unroll
      for (int r=0;r<4;r++)
        vvv[mb*4+r] = vg[(size_t)(16*mb+4*q4+r)*D_];
    if (tid < 64){
      cgr = cumg_all[((size_t)c*32+bh)*64 + tid];
      bvr = beta[(rowbase+tid)*H_ + h];
    }
  };

  prefetch(0);

  for (int c=0; c<64; ++c){
    size_t rowbase = ((size_t)b*T_ + c*64);

    // ---- write staged regs -> LDS ----
    #pragma unroll
    for (int i=0;i<4;i++){
      int g = tid + i*256; int s = g>>4; int k8 = (g&15)*8;
      *(uint4*)&Ksh[s*136+k8] = kv[i];
      *(uint4*)&Qsh[s*136+k8] = qv[i];
    }
    // Kt: pair lanes (s even, s odd) via shfl_xor(16) -> b32 writes of (t0,t0+1)
    #pragma unroll
    for (int i=0;i<4;i++){
      int g = tid + i*256; int s = g>>4; int kb8 = (g&15)*8;
      uint4 pv;
      pv.x = (unsigned)__shfl_xor((int)kv[i].x, 16);
      pv.y = (unsigned)__shfl_xor((int)kv[i].y, 16);
      pv.z = (unsigned)__shfl_xor((int)kv[i].z, 16);
      pv.w = (unsigned)__shfl_xor((int)kv[i].w, 16);
      int odd = s & 1;
      int t0  = s & ~1;
      int jb  = odd ? 4 : 0;
      int rot = (8*(g&15)) & 63;       // 8*(k>>3)
      const u16* own = (const u16*)&kv[i];
      const u16* par = (const u16*)&pv;
      #pragma unroll
      for (int j=0;j<4;j++){
        int jj = jb + j;
        unsigned lo = odd ? par[jj] : own[jj];
        unsigned hi = odd ? own[jj] : par[jj];
        int addr = (kb8+jj)*72 + ((t0 + rot) & 63);
        *(unsigned*)&Kt[addr] = lo | (hi << 16);
      }
    }
    #pragma unroll
    for (int i=0;i<2;i++){
      int g = tid+i*256; int r = g>>3; int c8=(g&7)*8;
      *(uint4*)&Ts[r*72+c8]  = tv[i];
      *(uint4*)&As_[r*72+c8] = av[i];
    }
    if (tid < 64){ cg[tid] = cgr; bv[tid] = bvr; }

    float vreg[16];
    #pragma unroll
    for (int i=0;i<16;i++) vreg[i] = bf2f(vvv[i]);

    // S0 -> bf16 transposed LDS (wave-local region)
    #pragma unroll
    for (int mb=0; mb<8; mb++){
      ushort4 w4;
      w4.x=f2bf(Sa[mb][0]); w4.y=f2bf(Sa[mb][1]); w4.z=f2bf(Sa[mb][2]); w4.w=f2bf(Sa[mb][3]);
      *(ushort4*)&Sbt[(wv*16+n)*136 + mb*16 + q4*4] = w4;
    }
    __syncthreads();

    if (c+1 < 64) prefetch(c+1);   // in flight across the whole compute phase

    // ---- P = K*S0, Oq = Q*S0 (all LDS) ----
    f32x4 Pa[4], Oqa[4];
    #pragma unroll
    for (int mb=0; mb<4; mb++){
      f32x4 p={0,0,0,0}, oq={0,0,0,0};
      #pragma unroll
      for (int ks=0; ks<4; ks++){
        bf16x8 ak = *(const bf16x8*)&Ksh[(16*mb+n)*136 + ks*32 + q4*8];
        bf16x8 aq = *(const bf16x8*)&Qsh[(16*mb+n)*136 + ks*32 + q4*8];
        bf16x8 bs = *(const bf16x8*)&Sbt[(wv*16+n)*136 + ks*32 + q4*8];
        p  = __builtin_amdgcn_mfma_f32_16x16x32_bf16(ak, bs, p, 0,0,0);
        oq = __builtin_amdgcn_mfma_f32_16x16x32_bf16(aq, bs, oq, 0,0,0);
      }
      Pa[mb]=p; Oqa[mb]=oq;
    }
    // ---- R = V - diag(g)P -> RUt (aliases Sbt; S0 fully consumed above, wave-local) ----
    #pragma unroll
    for (int mb=0; mb<4; mb++){
      ushort4 w4;
      #pragma unroll
      for (int r=0;r<4;r++){
        int t = 16*mb+4*q4+r;
        ((u16*)&w4)[r] = f2bf(vreg[mb*4+r] - cg[t]*Pa[mb][r]);
      }
      *(ushort4*)&RUt[(wv*16+n)*136 + mb*16 + q4*4] = w4;
    }
    // ---- U = T*R ----
    f32x4 Ua[4];
    #pragma unroll
    for (int mb=0; mb<4; mb++){
      f32x4 u={0,0,0,0};
      #pragma unroll
      for (int ks=0; ks<2; ks++){
        bf16x8 at = *(const bf16x8*)&Ts[(16*mb+n)*72 + ks*32 + q4*8];
        bf16x8 br = *(const bf16x8*)&RUt[(wv*16+n)*136 + ks*32 + q4*8];
        u = __builtin_amdgcn_mfma_f32_16x16x32_bf16(at, br, u, 0,0,0);
      }
      Ua[mb]=u;
    }
    // ---- raw U over RUt (for Att*U) ----
    #pragma unroll
    for (int mb=0; mb<4; mb++){
      ushort4 w4;
      #pragma unroll
      for (int r=0;r<4;r++) ((u16*)&w4)[r] = f2bf(Ua[mb][r]);
      *(ushort4*)&RUt[(wv*16+n)*136 + mb*16 + q4*4] = w4;
    }
    // ---- O = diag(g)Oq + Att*U ; store ----
    u16* og = o + rowbase*D_ + h*V_ + colb + n;
    #pragma unroll
    for (int mb=0; mb<4; mb++){
      f32x4 oa={0,0,0,0};
      #pragma unroll
      for (int ks=0; ks<2; ks++){
        bf16x8 aa = *(const bf16x8*)&As_[(16*mb+n)*72 + ks*32 + q4*8];
        bf16x8 bu = *(const bf16x8*)&RUt[(wv*16+n)*136 + ks*32 + q4*8];
        oa = __builtin_amdgcn_mfma_f32_16x16x32_bf16(aa, bu, oa, 0,0,0);
      }
      #pragma unroll
      for (int r=0;r<4;r++){
        int t = 16*mb+4*q4+r;
        og[(size_t)t*D_] = f2bf(cg[t]*Oqa[mb][r] + oa[r]);
      }
    }
    // ---- U'' = diag(gC*b/g) U over RUt ----
    float gC = cg[63];
    #pragma unroll
    for (int mb=0; mb<4; mb++){
      ushort4 w4;
      #pragma unroll
      for (int r=0;r<4;r++){
        int t = 16*mb+4*q4+r;
        ((u16*)&w4)[r] = f2bf((gC/cg[t])*bv[t]*Ua[mb][r]);
      }
      *(ushort4*)&RUt[(wv*16+n)*136 + mb*16 + q4*4] = w4;
    }
    // ---- S = gC*S + K^T * U'' (Kt reads use the rotate swizzle) ----
    #pragma unroll
    for (int mb=0; mb<8; mb++){
      f32x4 s = Sa[mb]*gC;
      int krow = 16*mb + n;
      int rot  = (16*mb + 8*(n>>3)) & 63;     // 8*(krow>>3) & 63
      #pragma unroll
      for (int ks=0; ks<2; ks++){
        int tt = (ks*32 + q4*8 + rot) & 63;
        bf16x8 akt = *(const bf16x8*)&Kt[krow*72 + tt];
        bf16x8 bu  = *(const bf16x8*)&RUt[(wv*16+n)*136 + ks*32 + q4*8];
        s = __builtin_amdgcn_mfma_f32_16x16x32_bf16(akt, bu, s, 0,0,0);
      }
      Sa[mb]=s;
    }
    __syncthreads();
  }
}

// ---------------- launch ----------------
extern "C" void kernel_launch(void* const* d_in, const int* in_sizes, int n_in,
                              void* d_out, int out_size, void* d_ws, size_t ws_size,
                              hipStream_t stream){
  const float* x    = (const float*)d_in[0];
  const float* Wq   = (const float*)d_in[1];
  const float* Wk   = (const float*)d_in[2];
  const float* Wv   = (const float*)d_in[3];
  const float* Wb   = (const float*)d_in[4];
  const float* Wa   = (const float*)d_in[5];
  const float* Wo   = (const float*)d_in[6];
  const float* ln1w = (const float*)d_in[7];
  const float* ln1b = (const float*)d_in[8];
  const float* ln2w = (const float*)d_in[9];
  const float* ln2b = (const float*)d_in[10];
  const float* W1   = (const float*)d_in[11];
  const float* b1   = (const float*)d_in[12];
  const float* W2   = (const float*)d_in[13];
  const float* b2   = (const float*)d_in[14];

  char* ws = (char*)d_ws;
  size_t off = 0;
  auto alloc = [&](size_t bytes)->char*{
    char* p = ws + off; off += (bytes + 255) & ~(size_t)255; return p;
  };
  u16* WqT = (u16*)alloc((size_t)1024*1024*2);
  u16* WkT = (u16*)alloc((size_t)1024*1024*2);
  u16* WvT = (u16*)alloc((size_t)1024*1024*2);
  u16* WoT = (u16*)alloc((size_t)1024*1024*2);
  u16* W1T = (u16*)alloc((size_t)4096*1024*2);
  u16* W2T = (u16*)alloc((size_t)1024*4096*2);
  u16* wabT = (u16*)alloc((size_t)16*1024*2);
  float* alphaB = (float*)alloc((size_t)N_TOK*H_*4);
  float* betaB  = (float*)alloc((size_t)N_TOK*H_*4);
  u16* x1 = (u16*)alloc((size_t)N_TOK*D_*2);
  u16* n1 = (u16*)alloc((size_t)N_TOK*D_*2);          // also reused: T_all+Att_all, then h (ln2 out)
  u16* qb = (u16*)alloc((size_t)N_TOK*D_*2);          // q,k,v,o contiguous (act_k relies on it)
  u16* kb = (u16*)alloc((size_t)N_TOK*D_*2);
  u16* vb = (u16*)alloc((size_t)N_TOK*D_*2);
  u16* ob = (u16*)alloc((size_t)N_TOK*D_*2);
  u16* ffa = qb;                                      // [N_TOK,4096] aliases q/k/v/o (dead by then)
  if (ws_size < off) return;

  u16*   T_all   = n1;                                 // 2048*4096 bf16 = 16.78 MB
  u16*   Att_all = n1 + (size_t)2048*4096;             // 16.78 MB
  float* cumg    = (float*)x1;                         // 0.5 MB (x1 dead till Wo-gemm)

  dim3 tb(32,8);
  transpose_k<<<dim3(32,32),  tb, 0, stream>>>(Wq, WqT, 1024, 1024);
  transpose_k<<<dim3(32,32),  tb, 0, stream>>>(Wk, WkT, 1024, 1024);
  transpose_k<<<dim3(32,32),  tb, 0, stream>>>(Wv, WvT, 1024, 1024);
  transpose_k<<<dim3(32,32),  tb, 0, stream>>>(Wo, WoT, 1024, 1024);
  transpose_k<<<dim3(128,32), tb, 0, stream>>>(W1, W1T, 1024, 4096);
  transpose_k<<<dim3(32,128), tb, 0, stream>>>(W2, W2T, 4096, 1024);
  wab_pack<<<64, 256, 0, stream>>>(Wb, Wa, wabT);

  ln_k<true><<<N_TOK, 256, 0, stream>>>(x, ln1w, ln1b, n1);

  gemm_k<0,false><<<dim3(8,128), 256, 0, stream>>>(n1, WqT, qb, N_TOK, 1024, 1024, nullptr, nullptr, nullptr);
  gemm_k<0,false><<<dim3(8,128), 256, 0, stream>>>(n1, WkT, kb, N_TOK, 1024, 1024, nullptr, nullptr, nullptr);
  gemm_k<0,false><<<dim3(8,128), 256, 0, stream>>>(n1, WvT, vb, N_TOK, 1024, 1024, nullptr, nullptr, nullptr);
  ab_k<<<256, 256, 0, stream>>>(n1, wabT, betaB, alphaB);
  act_k<<<dim3(N_TOK*H_, 3), 128, 0, stream>>>(qb);

  gdn_pre <<<dim3(64,32), 256, 0, stream>>>(kb, qb, alphaB, betaB, T_all, Att_all, cumg);
  gdn_scan<<<dim3(32,2),  256, 0, stream>>>(qb, kb, vb, betaB, T_all, Att_all, cumg, ob);

  gemm_k<1,false><<<dim3(8,128), 256, 0, stream>>>(ob, WoT, x1, N_TOK, 1024, 1024, x, nullptr, nullptr);
  ln_k<false><<<N_TOK, 256, 0, stream>>>(x1, ln2w, ln2b, n1);
  gemm_k<2,false><<<dim3(32,128), 256, 0, stream>>>(n1, W1T, ffa, N_TOK, 4096, 1024, nullptr, nullptr, b1);
  gemm_k<3,true><<<dim3(8,128), 256, 0, stream>>>(ffa, W2T, d_out, N_TOK, 1024, 4096, nullptr, x1, b2);
}